// Round 3
// baseline (502.504 us; speedup 1.0000x reference)
//
#include <hip/hip_runtime.h>
#include <hip/hip_bf16.h>
#include <cstdint>

typedef unsigned short u16;
typedef unsigned int u32;
typedef __bf16 bf16x8 __attribute__((ext_vector_type(8)));
typedef float f32x4 __attribute__((ext_vector_type(4)));
typedef u16 u16x8 __attribute__((ext_vector_type(8)));

#define DEVINL __device__ __forceinline__

DEVINL u16 f2bf(float f) {  // RNE f32 -> bf16 bits
  union { float f; u32 i; } x; x.f = f;
  u32 r = x.i + 0x7FFFu + ((x.i >> 16) & 1u);
  return (u16)(r >> 16);
}

// Load 8 elements at element-index idx from base; BF: bf16 bits, else f32
// (converted to bf16 RNE by the compiler's native cvt).
template <bool BF>
DEVINL bf16x8 ld8(const void* base, size_t idx) {
  if (BF) {
    return *(const bf16x8*)((const u16*)base + idx);
  } else {
    const float* f = (const float*)base + idx;
    float4 a = *(const float4*)f;
    float4 b = *(const float4*)(f + 4);
    bf16x8 r;
    r[0] = (__bf16)a.x; r[1] = (__bf16)a.y; r[2] = (__bf16)a.z; r[3] = (__bf16)a.w;
    r[4] = (__bf16)b.x; r[5] = (__bf16)b.y; r[6] = (__bf16)b.z; r[7] = (__bf16)b.w;
    return r;
  }
}

// ---------------------------------------------------------------------------
// NT GEMM: C[m,n] = sum_p sum_k Ap[m,k] * Bp[n,k]  (+f32 bias, opt tanh)
// Tile BM=128, BN=64, BK=32; 256 thr = 4 waves; wave w owns rows [w*32,w*32+32)
// as 2x4 grid of 16x16x32 bf16 MFMA fragments. Register-staged LDS.
// ---------------------------------------------------------------------------
template <int NP, bool A0BF, bool A1BF, bool OUT_BF16, bool TANH>
__global__ __launch_bounds__(256) void gemm_nt(
    const void* __restrict__ A0, const void* __restrict__ A1, int lda,
    const float* __restrict__ B0, const float* __restrict__ B1, int ldb,
    const float* __restrict__ bias0, const float* __restrict__ bias1,
    void* __restrict__ Cout, int ldc, int K) {
  __shared__ u16 As[NP][128 * 32];
  __shared__ u16 Bs[NP][64 * 32];
  const int tid = threadIdx.x;
  const int lane = tid & 63;
  const int w = tid >> 6;
  const int n0 = blockIdx.x * 64;
  const int m0 = blockIdx.y * 128;

  f32x4 acc[2][4];
#pragma unroll
  for (int i = 0; i < 2; ++i)
#pragma unroll
    for (int j = 0; j < 4; ++j) acc[i][j] = (f32x4)0.f;

  const int kk = (lane >> 4) << 3;  // k-offset of this lane's 8 elems
  const int rl = lane & 15;         // row (A) / col (B) within fragment
  const int srow = tid >> 2;        // staging: row within tile (0..63)
  const int scb = tid & 3;          // staging: 8-elem chunk within row

  for (int k0 = 0; k0 < K; k0 += 32) {
    // Global loads -> regs (issued before barrier, overlap w/ prev MFMA)
    bf16x8 a00 = ld8<A0BF>(A0, (size_t)(m0 + srow) * lda + k0 + scb * 8);
    bf16x8 a01 = ld8<A0BF>(A0, (size_t)(m0 + 64 + srow) * lda + k0 + scb * 8);
    bf16x8 b0v = ld8<false>(B0, (size_t)(n0 + srow) * ldb + k0 + scb * 8);
    bf16x8 a10, a11, b1v;
    if (NP == 2) {
      a10 = ld8<A1BF>(A1, (size_t)(m0 + srow) * lda + k0 + scb * 8);
      a11 = ld8<A1BF>(A1, (size_t)(m0 + 64 + srow) * lda + k0 + scb * 8);
      b1v = ld8<false>(B1, (size_t)(n0 + srow) * ldb + k0 + scb * 8);
    }
    __syncthreads();  // prev iteration's LDS readers done
    *(bf16x8*)&As[0][srow * 32 + scb * 8] = a00;
    *(bf16x8*)&As[0][(64 + srow) * 32 + scb * 8] = a01;
    *(bf16x8*)&Bs[0][srow * 32 + scb * 8] = b0v;
    if (NP == 2) {
      *(bf16x8*)&As[1][srow * 32 + scb * 8] = a10;
      *(bf16x8*)&As[1][(64 + srow) * 32 + scb * 8] = a11;
      *(bf16x8*)&Bs[1][srow * 32 + scb * 8] = b1v;
    }
    __syncthreads();  // staging visible
#pragma unroll
    for (int p = 0; p < NP; ++p) {
      bf16x8 a0 = *(const bf16x8*)&As[p][(w * 32 + rl) * 32 + kk];
      bf16x8 a1 = *(const bf16x8*)&As[p][(w * 32 + 16 + rl) * 32 + kk];
#pragma unroll
      for (int nt = 0; nt < 4; ++nt) {
        bf16x8 b = *(const bf16x8*)&Bs[p][(nt * 16 + rl) * 32 + kk];
        acc[0][nt] = __builtin_amdgcn_mfma_f32_16x16x32_bf16(a0, b, acc[0][nt], 0, 0, 0);
        acc[1][nt] = __builtin_amdgcn_mfma_f32_16x16x32_bf16(a1, b, acc[1][nt], 0, 0, 0);
      }
    }
  }

  // Epilogue. C/D layout: col = lane&15, row = (lane>>4)*4 + reg.
  const int rq = lane >> 4;
#pragma unroll
  for (int nt = 0; nt < 4; ++nt) {
    int gc = n0 + nt * 16 + rl;
    float bia = 0.f;
    if (bias0) bia += bias0[gc];
    if (NP == 2 && bias1) bia += bias1[gc];
#pragma unroll
    for (int mt = 0; mt < 2; ++mt) {
#pragma unroll
      for (int r = 0; r < 4; ++r) {
        int gr = m0 + w * 32 + mt * 16 + rq * 4 + r;
        float v = acc[mt][nt][r] + bia;
        if (TANH) v = tanhf(v);
        if (OUT_BF16)
          ((u16*)Cout)[(size_t)gr * ldc + gc] = f2bf(v);
        else
          ((float*)Cout)[(size_t)gr * ldc + gc] = v;
      }
    }
  }
}

// ---------------------------------------------------------------------------
// NN GEMM (per batch): mix[l,d] = sum_w alpha[l,w] * ctx[w,d]
// alpha f32 [512,512], ctx f32 [512,1024] -> mix bf16. B transposed in LDS.
// ---------------------------------------------------------------------------
__global__ __launch_bounds__(256) void gemm_nn_mix(
    const float* __restrict__ alpha, const float* __restrict__ ctx,
    u16* __restrict__ mix) {
  __shared__ u16 As[128 * 32];
  __shared__ u16 Bs[64 * 32];  // [n][k]
  const int tid = threadIdx.x, lane = tid & 63, w = tid >> 6;
  const int b = blockIdx.z;
  const int n0 = blockIdx.x * 64, m0 = blockIdx.y * 128;
  const float* A = alpha + (size_t)b * 512 * 512;
  const float* Bg = ctx + (size_t)b * 512 * 1024;
  u16* C = mix + (size_t)b * 512 * 1024;

  f32x4 acc[2][4];
#pragma unroll
  for (int i = 0; i < 2; ++i)
#pragma unroll
    for (int j = 0; j < 4; ++j) acc[i][j] = (f32x4)0.f;

  const int kk = (lane >> 4) << 3;
  const int rl = lane & 15;
  const int srow = tid >> 2, scb = tid & 3;
  const int kl = tid & 31, nb = tid >> 5;  // B staging: k row, n block

  for (int k0 = 0; k0 < 512; k0 += 32) {
    bf16x8 a0v = ld8<false>(A, (size_t)(m0 + srow) * 512 + k0 + scb * 8);
    bf16x8 a1v = ld8<false>(A, (size_t)(m0 + 64 + srow) * 512 + k0 + scb * 8);
    bf16x8 bv = ld8<false>(Bg, (size_t)(k0 + kl) * 1024 + n0 + nb * 8);
    __syncthreads();
    *(bf16x8*)&As[srow * 32 + scb * 8] = a0v;
    *(bf16x8*)&As[(64 + srow) * 32 + scb * 8] = a1v;
#pragma unroll
    for (int j = 0; j < 8; ++j) {
      __bf16 h = bv[j];
      Bs[(nb * 8 + j) * 32 + kl] = *(const u16*)&h;
    }
    __syncthreads();

    bf16x8 a0 = *(const bf16x8*)&As[(w * 32 + rl) * 32 + kk];
    bf16x8 a1 = *(const bf16x8*)&As[(w * 32 + 16 + rl) * 32 + kk];
#pragma unroll
    for (int nt = 0; nt < 4; ++nt) {
      bf16x8 bb = *(const bf16x8*)&Bs[(nt * 16 + rl) * 32 + kk];
      acc[0][nt] = __builtin_amdgcn_mfma_f32_16x16x32_bf16(a0, bb, acc[0][nt], 0, 0, 0);
      acc[1][nt] = __builtin_amdgcn_mfma_f32_16x16x32_bf16(a1, bb, acc[1][nt], 0, 0, 0);
    }
  }

  const int rq = lane >> 4;
#pragma unroll
  for (int nt = 0; nt < 4; ++nt) {
    int gc = n0 + nt * 16 + rl;
#pragma unroll
    for (int mt = 0; mt < 2; ++mt) {
#pragma unroll
      for (int r = 0; r < 4; ++r) {
        int gr = m0 + w * 32 + mt * 16 + rq * 4 + r;
        C[(size_t)gr * 1024 + gc] = f2bf(acc[mt][nt][r]);
      }
    }
  }
}

// ---------------------------------------------------------------------------
// Row softmax, in-place on f32 scores: one wave per row of 512
// ---------------------------------------------------------------------------
__global__ __launch_bounds__(256) void softmax_rows_f32(float* __restrict__ S) {
  const int row = blockIdx.x * 4 + (threadIdx.x >> 6);
  const int lane = threadIdx.x & 63;
  float* s = S + (size_t)row * 512 + lane * 8;
  float4 v0 = *(const float4*)s;
  float4 v1 = *(const float4*)(s + 4);
  float vs[8] = {v0.x, v0.y, v0.z, v0.w, v1.x, v1.y, v1.z, v1.w};
  float vm = vs[0];
#pragma unroll
  for (int j = 1; j < 8; ++j) vm = fmaxf(vm, vs[j]);
#pragma unroll
  for (int off = 32; off > 0; off >>= 1) vm = fmaxf(vm, __shfl_xor(vm, off, 64));
  float e[8];
  float sum = 0.f;
#pragma unroll
  for (int j = 0; j < 8; ++j) {
    e[j] = __expf(vs[j] - vm);
    sum += e[j];
  }
#pragma unroll
  for (int off = 32; off > 0; off >>= 1) sum += __shfl_xor(sum, off, 64);
  float inv = 1.f / sum;
  float4 o0 = {e[0] * inv, e[1] * inv, e[2] * inv, e[3] * inv};
  float4 o1 = {e[4] * inv, e[5] * inv, e[6] * inv, e[7] * inv};
  *(float4*)s = o0;
  *(float4*)(s + 4) = o1;
}

// ---------------------------------------------------------------------------
extern "C" void kernel_launch(void* const* d_in, const int* in_sizes, int n_in,
                              void* d_out, int out_size, void* d_ws, size_t ws_size,
                              hipStream_t stream) {
  const float* query = (const float*)d_in[0];  // [32,512,1024] f32
  const float* ctx   = (const float*)d_in[1];  // [32,512,1024]
  const float* W_in  = (const float*)d_in[2];  // [1024,1024]
  const float* b_in  = (const float*)d_in[3];  // [1024]
  const float* W_in2 = (const float*)d_in[4];  // [1024,1024]
  const float* b_in2 = (const float*)d_in[5];  // [1024]
  const float* W_out = (const float*)d_in[6];  // [512,1024]
  const float* W_fc  = (const float*)d_in[7];  // [1024,2048]
  const float* b_fc  = (const float*)d_in[8];  // [1024]

  float* out   = (float*)d_out;               // [32*512*1024] f32
  float* alpha = (float*)d_out + 16777216;    // [32*512*512] f32 (scores too)

  u16* t_ws = (u16*)d_ws;  // 33.6 MB bf16 tanh(q+c); region reused for mix
  u16* mix  = (u16*)d_ws;

  dim3 blk(256, 1, 1);

  // K1: t = tanh(query@W_in^T + ctx@W_in2^T + b_in + b_in2)  -> bf16 ws
  gemm_nt<2, false, false, true, true><<<dim3(16, 128, 1), blk, 0, stream>>>(
      query, ctx, 1024, W_in, W_in2, 1024, b_in, b_in2, t_ws, 1024, 1024);

  // K2: scores = t @ W_out^T -> f32, directly into alpha slot of d_out
  gemm_nt<1, true, true, false, false><<<dim3(8, 128, 1), blk, 0, stream>>>(
      t_ws, nullptr, 1024, W_out, nullptr, 1024, nullptr, nullptr, alpha, 512,
      1024);

  // K3: alpha = softmax(scores), in-place f32
  softmax_rows_f32<<<dim3(4096, 1, 1), blk, 0, stream>>>(alpha);

  // K4: mix = alpha @ ctx (per batch) -> bf16 ws (t region, t dead)
  gemm_nn_mix<<<dim3(16, 4, 32), blk, 0, stream>>>(alpha, ctx, mix);

  // K5: out = mix@W_fc[:,:1024]^T + ctx@W_fc[:,1024:]^T + b_fc  -> f32
  gemm_nt<2, true, false, false, false><<<dim3(16, 128, 1), blk, 0, stream>>>(
      mix, ctx, 1024, W_fc, W_fc + 1024, 2048, b_fc, nullptr, out, 1024, 1024);
}

// Round 4
// 389.012 us; speedup vs baseline: 1.2917x; 1.2917x over previous
//
#include <hip/hip_runtime.h>
#include <hip/hip_bf16.h>
#include <cstdint>

typedef unsigned short u16;
typedef unsigned int u32;
typedef __bf16 bf16x8 __attribute__((ext_vector_type(8)));
typedef float f32x4 __attribute__((ext_vector_type(4)));
typedef u16 u16x8 __attribute__((ext_vector_type(8)));

#define DEVINL __device__ __forceinline__

typedef __attribute__((address_space(1))) const u32 gbl_u32;
typedef __attribute__((address_space(3))) u32 lds_u32;

// async global->LDS, 16B/lane; dest = wave-uniform base + lane*16
DEVINL void llds16(const void* g, void* l) {
  __builtin_amdgcn_global_load_lds((gbl_u32*)g, (lds_u32*)l, 16, 0, 0);
}

DEVINL u16 f2bf(float f) {  // RNE f32->bf16 bits
  union { float f; u32 i; } x; x.f = f;
  u32 r = x.i + 0x7FFFu + ((x.i >> 16) & 1u);
  return (u16)(r >> 16);
}

DEVINL float fast_tanh(float x) {
  x = fminf(10.f, fmaxf(-10.f, x));
  float e = __expf(2.f * x);
  return (e - 1.f) / (e + 1.f);
}

DEVINL bf16x8 cvt8(const float4& a, const float4& b) {
  bf16x8 r;
  r[0] = (__bf16)a.x; r[1] = (__bf16)a.y; r[2] = (__bf16)a.z; r[3] = (__bf16)a.w;
  r[4] = (__bf16)b.x; r[5] = (__bf16)b.y; r[6] = (__bf16)b.z; r[7] = (__bf16)b.w;
  return r;
}

// ---------------------------------------------------------------------------
// f32 -> bf16 elementwise convert, 8 elems/thread
// ---------------------------------------------------------------------------
__global__ __launch_bounds__(256) void cvtk(const float* __restrict__ src,
                                            u16* __restrict__ dst, int n8) {
  int i = blockIdx.x * 256 + threadIdx.x;
  if (i >= n8) return;
  const float* s = src + (size_t)i * 8;
  float4 a = *(const float4*)s;
  float4 b = *(const float4*)(s + 4);
  *(bf16x8*)(dst + (size_t)i * 8) = cvt8(a, b);
}

// ---------------------------------------------------------------------------
// Segmented NT GEMM: C[m,n] = sum_s sum_k As[m,k]*Bs[n,k]  (+bias, opt tanh)
// BM=BN=128, BK=32; 256 thr = 4 waves in 2x2 grid; wave = 4x4 16x16x32 frags.
// 2-phase double-buffered: stage(t+1) || compute(t), one barrier per K-step.
// B-side always bf16 via global_load_lds. A per-segment bf16(gll) or f32(reg).
// ---------------------------------------------------------------------------
template <int NSEG, bool S0BF, bool S1BF, bool OUT_BF16, bool TANH>
__global__ __launch_bounds__(256) void gemm_nt2(
    const void* __restrict__ A0v, const void* __restrict__ A1v, int lda,
    const u16* __restrict__ B0, const u16* __restrict__ B1, int ldb0, int ldb1,
    const float* __restrict__ bias0, const float* __restrict__ bias1,
    void* __restrict__ Cout, int ldc, int Kseg) {
  __shared__ u16 As[2][4096];
  __shared__ u16 Bs[2][4096];
  const int tid = threadIdx.x, lane = tid & 63, w = tid >> 6;
  const int wr = w >> 1, wc = w & 1;
  const int n0 = blockIdx.x * 128, m0 = blockIdx.y * 128;
  const int kk = (lane >> 4) << 3, rl = lane & 15;

  f32x4 acc[4][4];
#pragma unroll
  for (int i = 0; i < 4; ++i)
#pragma unroll
    for (int j = 0; j < 4; ++j) acc[i][j] = (f32x4)0.f;

  float4 fr[4];  // staged f32 A regs (held across compute; T14 split)
  const int NT0 = Kseg >> 5;
  const int NT = NSEG * NT0;

  // chunk maps: 512 chunks of 16B per 128x32 tile
  const int c0 = tid, c1 = 256 + tid;                    // f32 reg-staging map
  const int gb0 = w * 64, gb1 = 256 + w * 64;            // gll wave-uniform bases
  const int ch0 = gb0 + lane, ch1 = gb1 + lane;          // gll per-lane chunks

  auto stage = [&](int t, int buf) {
    const int seg = (NSEG == 2 && t >= NT0) ? 1 : 0;
    const int kl = (t - seg * NT0) << 5;
    {  // B tile: always bf16 gll
      const u16* Bp = seg ? B1 : B0;
      const int ldb = seg ? ldb1 : ldb0;
      llds16(Bp + (size_t)(n0 + (ch0 >> 2)) * ldb + kl + (ch0 & 3) * 8,
             &Bs[buf][gb0 * 8]);
      llds16(Bp + (size_t)(n0 + (ch1 >> 2)) * ldb + kl + (ch1 & 3) * 8,
             &Bs[buf][gb1 * 8]);
    }
    const bool abf = seg ? S1BF : S0BF;
    if (abf) {
      const u16* Ap = (const u16*)(seg ? A1v : A0v);
      llds16(Ap + (size_t)(m0 + (ch0 >> 2)) * lda + kl + (ch0 & 3) * 8,
             &As[buf][gb0 * 8]);
      llds16(Ap + (size_t)(m0 + (ch1 >> 2)) * lda + kl + (ch1 & 3) * 8,
             &As[buf][gb1 * 8]);
    } else {
      const float* Ap = (const float*)(seg ? A1v : A0v);
      const float* p0 = Ap + (size_t)(m0 + (c0 >> 2)) * lda + kl + (c0 & 3) * 8;
      const float* p1 = Ap + (size_t)(m0 + (c1 >> 2)) * lda + kl + (c1 & 3) * 8;
      fr[0] = *(const float4*)p0;
      fr[1] = *(const float4*)(p0 + 4);
      fr[2] = *(const float4*)p1;
      fr[3] = *(const float4*)(p1 + 4);
    }
  };
  auto stage_fin = [&](int t, int buf) {
    const int seg = (NSEG == 2 && t >= NT0) ? 1 : 0;
    const bool abf = seg ? S1BF : S0BF;
    if (!abf) {
      *(bf16x8*)&As[buf][c0 * 8] = cvt8(fr[0], fr[1]);
      *(bf16x8*)&As[buf][c1 * 8] = cvt8(fr[2], fr[3]);
    }
  };
  auto compute = [&](int buf) {
    bf16x8 af[4], bfv[4];
#pragma unroll
    for (int i = 0; i < 4; ++i)
      af[i] = *(const bf16x8*)&As[buf][(wr * 64 + i * 16 + rl) * 32 + kk];
#pragma unroll
    for (int j = 0; j < 4; ++j)
      bfv[j] = *(const bf16x8*)&Bs[buf][(wc * 64 + j * 16 + rl) * 32 + kk];
#pragma unroll
    for (int i = 0; i < 4; ++i)
#pragma unroll
      for (int j = 0; j < 4; ++j)
        acc[i][j] =
            __builtin_amdgcn_mfma_f32_16x16x32_bf16(af[i], bfv[j], acc[i][j], 0, 0, 0);
  };

  stage(0, 0);
  stage_fin(0, 0);
  __syncthreads();
  for (int t = 0; t < NT; ++t) {
    const int cb = t & 1;
    if (t + 1 < NT) stage(t + 1, cb ^ 1);  // loads in flight over compute
    compute(cb);
    if (t + 1 < NT) stage_fin(t + 1, cb ^ 1);
    __syncthreads();  // drains vmcnt (gll) + lgkm; flips buffers
  }

  // Epilogue. C/D: col = lane&15, row = (lane>>4)*4 + reg.
  const int rq = lane >> 4;
#pragma unroll
  for (int j = 0; j < 4; ++j) {
    const int gc = n0 + wc * 64 + j * 16 + rl;
    float bia = 0.f;
    if (bias0) bia += bias0[gc];
    if (NSEG == 2 && bias1) bia += bias1[gc];
#pragma unroll
    for (int i = 0; i < 4; ++i) {
#pragma unroll
      for (int r = 0; r < 4; ++r) {
        const int grow = m0 + wr * 64 + i * 16 + rq * 4 + r;
        float v = acc[i][j][r] + bia;
        if (TANH) v = fast_tanh(v);
        if (OUT_BF16)
          ((u16*)Cout)[(size_t)grow * ldc + gc] = f2bf(v);
        else
          ((float*)Cout)[(size_t)grow * ldc + gc] = v;
      }
    }
  }
}

// ---------------------------------------------------------------------------
// NN GEMM (per batch): mix[l,d] = sum_w alpha[l,w]*ctx[w,d]
// A = alpha f32 (reg-cvt staging); B = ctx (bf16 or f32), transposed in LDS.
// Same 128x128/BK=32/2-phase structure.
// ---------------------------------------------------------------------------
template <bool CTXBF>
__global__ __launch_bounds__(256) void gemm_nn2(
    const float* __restrict__ alpha, const void* __restrict__ ctxv,
    u16* __restrict__ mix) {
  __shared__ u16 As[2][4096];
  __shared__ u16 Bs[2][4096];
  const int tid = threadIdx.x, lane = tid & 63, w = tid >> 6;
  const int wr = w >> 1, wc = w & 1;
  const int b = blockIdx.z;
  const int n0 = blockIdx.x * 128, m0 = blockIdx.y * 128;
  const int kk = (lane >> 4) << 3, rl = lane & 15;
  const float* A = alpha + (size_t)b * 262144;  // [512,512]
  u16* C = mix + (size_t)b * 524288;            // [512,1024]

  f32x4 acc[4][4];
#pragma unroll
  for (int i = 0; i < 4; ++i)
#pragma unroll
    for (int j = 0; j < 4; ++j) acc[i][j] = (f32x4)0.f;

  float4 fr[4];
  u16x8 ub[2];
  float4 fb[4];
  const int c0 = tid, c1 = 256 + tid;
  const int kl = tid & 31, ng = tid >> 5;  // B: k row, 16-col group

  auto stage = [&](int t, int buf) {
    const int k0 = t << 5;
    const float* p0 = A + (size_t)(m0 + (c0 >> 2)) * 512 + k0 + (c0 & 3) * 8;
    const float* p1 = A + (size_t)(m0 + (c1 >> 2)) * 512 + k0 + (c1 & 3) * 8;
    fr[0] = *(const float4*)p0;
    fr[1] = *(const float4*)(p0 + 4);
    fr[2] = *(const float4*)p1;
    fr[3] = *(const float4*)(p1 + 4);
    if (CTXBF) {
      const u16* Cb = (const u16*)ctxv + (size_t)b * 524288 +
                      (size_t)(k0 + kl) * 1024 + n0 + ng * 16;
      ub[0] = *(const u16x8*)Cb;
      ub[1] = *(const u16x8*)(Cb + 8);
    } else {
      const float* Cf = (const float*)ctxv + (size_t)b * 524288 +
                        (size_t)(k0 + kl) * 1024 + n0 + ng * 16;
      fb[0] = *(const float4*)Cf;
      fb[1] = *(const float4*)(Cf + 4);
      fb[2] = *(const float4*)(Cf + 8);
      fb[3] = *(const float4*)(Cf + 12);
    }
  };
  auto stage_fin = [&](int buf) {
    *(bf16x8*)&As[buf][c0 * 8] = cvt8(fr[0], fr[1]);
    *(bf16x8*)&As[buf][c1 * 8] = cvt8(fr[2], fr[3]);
    u16 vals[16];
    if (CTXBF) {
#pragma unroll
      for (int j = 0; j < 8; ++j) { vals[j] = ub[0][j]; vals[8 + j] = ub[1][j]; }
    } else {
      bf16x8 x = cvt8(fb[0], fb[1]), y = cvt8(fb[2], fb[3]);
#pragma unroll
      for (int j = 0; j < 8; ++j) {
        __bf16 hx = x[j], hy = y[j];
        vals[j] = *(const u16*)&hx;
        vals[8 + j] = *(const u16*)&hy;
      }
    }
#pragma unroll
    for (int j = 0; j < 16; ++j)
      Bs[buf][(ng * 16 + j) * 32 + kl] = vals[j];  // transpose write
  };
  auto compute = [&](int buf) {
    bf16x8 af[4], bfv[4];
#pragma unroll
    for (int i = 0; i < 4; ++i)
      af[i] = *(const bf16x8*)&As[buf][(wr * 64 + i * 16 + rl) * 32 + kk];
#pragma unroll
    for (int j = 0; j < 4; ++j)
      bfv[j] = *(const bf16x8*)&Bs[buf][(wc * 64 + j * 16 + rl) * 32 + kk];
#pragma unroll
    for (int i = 0; i < 4; ++i)
#pragma unroll
      for (int j = 0; j < 4; ++j)
        acc[i][j] =
            __builtin_amdgcn_mfma_f32_16x16x32_bf16(af[i], bfv[j], acc[i][j], 0, 0, 0);
  };

  stage(0, 0);
  stage_fin(0);
  __syncthreads();
  for (int t = 0; t < 16; ++t) {
    const int cb = t & 1;
    if (t + 1 < 16) stage(t + 1, cb ^ 1);
    compute(cb);
    if (t + 1 < 16) stage_fin(cb ^ 1);
    __syncthreads();
  }

  const int rq = lane >> 4;
#pragma unroll
  for (int j = 0; j < 4; ++j) {
    const int gc = n0 + wc * 64 + j * 16 + rl;
#pragma unroll
    for (int i = 0; i < 4; ++i) {
#pragma unroll
      for (int r = 0; r < 4; ++r) {
        const int grow = m0 + wr * 64 + i * 16 + rq * 4 + r;
        C[(size_t)grow * 1024 + gc] = f2bf(acc[i][j][r]);
      }
    }
  }
}

// ---------------------------------------------------------------------------
// Row softmax, in-place f32: one wave per row of 512
// ---------------------------------------------------------------------------
__global__ __launch_bounds__(256) void softmax_rows_f32(float* __restrict__ S) {
  const int row = blockIdx.x * 4 + (threadIdx.x >> 6);
  const int lane = threadIdx.x & 63;
  float* s = S + (size_t)row * 512 + lane * 8;
  float4 v0 = *(const float4*)s;
  float4 v1 = *(const float4*)(s + 4);
  float vs[8] = {v0.x, v0.y, v0.z, v0.w, v1.x, v1.y, v1.z, v1.w};
  float vm = vs[0];
#pragma unroll
  for (int j = 1; j < 8; ++j) vm = fmaxf(vm, vs[j]);
#pragma unroll
  for (int off = 32; off > 0; off >>= 1) vm = fmaxf(vm, __shfl_xor(vm, off, 64));
  float e[8];
  float sum = 0.f;
#pragma unroll
  for (int j = 0; j < 8; ++j) {
    e[j] = __expf(vs[j] - vm);
    sum += e[j];
  }
#pragma unroll
  for (int off = 32; off > 0; off >>= 1) sum += __shfl_xor(sum, off, 64);
  float inv = 1.f / sum;
  float4 o0 = {e[0] * inv, e[1] * inv, e[2] * inv, e[3] * inv};
  float4 o1 = {e[4] * inv, e[5] * inv, e[6] * inv, e[7] * inv};
  *(float4*)s = o0;
  *(float4*)(s + 4) = o1;
}

// ---------------------------------------------------------------------------
extern "C" void kernel_launch(void* const* d_in, const int* in_sizes, int n_in,
                              void* d_out, int out_size, void* d_ws, size_t ws_size,
                              hipStream_t stream) {
  const float* query = (const float*)d_in[0];  // [32,512,1024] f32
  const float* ctx   = (const float*)d_in[1];  // [32,512,1024]
  const float* W_in  = (const float*)d_in[2];  // [1024,1024]
  const float* b_in  = (const float*)d_in[3];  // [1024]
  const float* W_in2 = (const float*)d_in[4];  // [1024,1024]
  const float* b_in2 = (const float*)d_in[5];  // [1024]
  const float* W_out = (const float*)d_in[6];  // [512,1024]
  const float* W_fc  = (const float*)d_in[7];  // [1024,2048]
  const float* b_fc  = (const float*)d_in[8];  // [1024]

  float* out   = (float*)d_out;               // [32*512*1024] f32
  float* alpha = (float*)d_out + 16777216;    // [32*512*512] f32 (scores too)

  // ws layout: [wbf 9.4MB][t/mix 33.55MB][cbf 33.55MB (plan B only)]
  u16* wibf  = (u16*)d_ws;                  // 1048576
  u16* wi2bf = wibf + 1048576;              // 1048576
  u16* wobf  = wibf + 2097152;              // 524288
  u16* wfbf  = wibf + 2621440;              // 2097152
  u16* t_ws  = (u16*)((char*)d_ws + 9437184);   // 16777216 elems (t, then mix)
  u16* cbf   = (u16*)((char*)d_ws + 42991616);  // 16777216 elems
  const bool planB = ws_size >= 76546048ull;

  dim3 blk(256, 1, 1);

  // K0: weight converts (+ ctx if plan B)
  cvtk<<<dim3(512), blk, 0, stream>>>(W_in, wibf, 131072);
  cvtk<<<dim3(512), blk, 0, stream>>>(W_in2, wi2bf, 131072);
  cvtk<<<dim3(256), blk, 0, stream>>>(W_out, wobf, 65536);
  cvtk<<<dim3(1024), blk, 0, stream>>>(W_fc, wfbf, 262144);
  if (planB) cvtk<<<dim3(8192), blk, 0, stream>>>(ctx, cbf, 2097152);

  // K1: t = tanh(query@W_in^T + ctx@W_in2^T + b_in + b_in2) -> bf16
  if (planB)
    gemm_nt2<2, false, true, true, true><<<dim3(8, 128), blk, 0, stream>>>(
        query, cbf, 1024, wibf, wi2bf, 1024, 1024, b_in, b_in2, t_ws, 1024, 1024);
  else
    gemm_nt2<2, false, false, true, true><<<dim3(8, 128), blk, 0, stream>>>(
        query, ctx, 1024, wibf, wi2bf, 1024, 1024, b_in, b_in2, t_ws, 1024, 1024);

  // K2: scores = t @ W_out^T -> f32 into alpha slot
  gemm_nt2<1, true, true, false, false><<<dim3(4, 128), blk, 0, stream>>>(
      t_ws, nullptr, 1024, wobf, nullptr, 1024, 1024, nullptr, nullptr, alpha,
      512, 1024);

  // K3: softmax in-place
  softmax_rows_f32<<<dim3(4096), blk, 0, stream>>>(alpha);

  // K4: mix = alpha @ ctx -> bf16 (reuses t region; t dead after K2)
  if (planB)
    gemm_nn2<true><<<dim3(8, 4, 32), blk, 0, stream>>>(alpha, cbf, t_ws);
  else
    gemm_nn2<false><<<dim3(8, 4, 32), blk, 0, stream>>>(alpha, ctx, t_ws);

  // K5: out = mix@W_fc[:, :1024]^T + ctx@W_fc[:, 1024:]^T + b_fc -> f32
  if (planB)
    gemm_nt2<2, true, true, false, false><<<dim3(8, 128), blk, 0, stream>>>(
        t_ws, cbf, 1024, wfbf, wfbf + 1024, 2048, 2048, b_fc, nullptr, out,
        1024, 1024);
  else
    gemm_nt2<2, true, false, false, false><<<dim3(8, 128), blk, 0, stream>>>(
        t_ws, ctx, 1024, wfbf, wfbf + 1024, 2048, 2048, b_fc, nullptr, out,
        1024, 1024);
}

// Round 5
// 385.908 us; speedup vs baseline: 1.3021x; 1.0080x over previous
//
#include <hip/hip_runtime.h>
#include <hip/hip_bf16.h>
#include <cstdint>

typedef unsigned short u16;
typedef unsigned int u32;
typedef __bf16 bf16x8 __attribute__((ext_vector_type(8)));
typedef float f32x4 __attribute__((ext_vector_type(4)));
typedef u16 u16x8 __attribute__((ext_vector_type(8)));

#define DEVINL __device__ __forceinline__

typedef __attribute__((address_space(1))) const u32 gbl_u32;
typedef __attribute__((address_space(3))) u32 lds_u32;

// async global->LDS, 16B/lane; dest = wave-uniform base + lane*16
DEVINL void llds16(const void* g, void* l) {
  __builtin_amdgcn_global_load_lds((gbl_u32*)g, (lds_u32*)l, 16, 0, 0);
}

DEVINL u16 f2bf(float f) {  // RNE f32->bf16 bits
  union { float f; u32 i; } x; x.f = f;
  u32 r = x.i + 0x7FFFu + ((x.i >> 16) & 1u);
  return (u16)(r >> 16);
}

DEVINL float fast_tanh(float x) {
  x = fminf(10.f, fmaxf(-10.f, x));
  float e = __expf(2.f * x);
  return (e - 1.f) / (e + 1.f);
}

DEVINL bf16x8 cvt8(const float4& a, const float4& b) {
  bf16x8 r;
  r[0] = (__bf16)a.x; r[1] = (__bf16)a.y; r[2] = (__bf16)a.z; r[3] = (__bf16)a.w;
  r[4] = (__bf16)b.x; r[5] = (__bf16)b.y; r[6] = (__bf16)b.z; r[7] = (__bf16)b.w;
  return r;
}

// ---------------------------------------------------------------------------
// f32 -> bf16 elementwise convert (natural layout), 8 elems/thread
// ---------------------------------------------------------------------------
__global__ __launch_bounds__(256) void cvtk(const float* __restrict__ src,
                                            u16* __restrict__ dst, int n8) {
  int i = blockIdx.x * 256 + threadIdx.x;
  if (i >= n8) return;
  const float* s = src + (size_t)i * 8;
  *(bf16x8*)(dst + (size_t)i * 8) = cvt8(*(const float4*)s, *(const float4*)(s + 4));
}

// ---------------------------------------------------------------------------
// Weight tiler: f32 [N][srcld] (k window koff..koff+1023) -> bf16 tiles.
// Tile (nb,kb) = 128x32; chunk (row,h) at unit u = h*128 + (row ^ (h<<1)).
// Global chunk offset = ((nb*32 + kb)*512 + u)*8 u16. K fixed = 1024 (K8=128).
// ---------------------------------------------------------------------------
__global__ __launch_bounds__(256) void tile_b(const float* __restrict__ src,
                                              int srcld, int koff,
                                              u16* __restrict__ dst, int nchunks) {
  int id = blockIdx.x * 256 + threadIdx.x;
  if (id >= nchunks) return;
  int n = id >> 7, k8 = id & 127;
  int kb = k8 >> 2, h = k8 & 3;
  int u = h * 128 + ((n & 127) ^ (h << 1));
  const float* s = src + (size_t)n * srcld + koff + k8 * 8;
  size_t dc = ((size_t)((n >> 7) * 32 + kb) * 512 + u) * 8;
  *(bf16x8*)(dst + dc) = cvt8(*(const float4*)s, *(const float4*)(s + 4));
}

// ---------------------------------------------------------------------------
// Segmented NT GEMM: C[m,n] = sum_s sum_k As[m,k]*Bs_w[n,k] (+bias, opt tanh)
// BM=BN=128, BK=32, Kseg=1024 (NT0=32). 256 thr = 4 waves (2x2), wave = 4x4
// 16x16x32 frags. B via pre-tiled gll (linear dest == swizzled layout);
// A reg-staged with swizzled ds_write. 2-phase dbuf. XCD-bijective swizzle.
// ---------------------------------------------------------------------------
template <int NSEG, bool S0BF, bool S1BF, bool OUT_BF16, bool TANH>
__global__ __launch_bounds__(256) void gemm_nt3(
    const void* __restrict__ A0v, const void* __restrict__ A1v, int lda,
    const u16* __restrict__ Bt0, const u16* __restrict__ Bt1,
    const float* __restrict__ bias0, const float* __restrict__ bias1,
    void* __restrict__ Cout, int ldc) {
  __shared__ u16 As[2][4096];
  __shared__ u16 Bs[2][4096];
  const int tid = threadIdx.x, lane = tid & 63, w = tid >> 6;
  const int wr = w >> 1, wc = w & 1;

  // XCD-bijective swizzle: contiguous grid chunk per XCD
  const int NX = gridDim.x;
  const int total = NX * gridDim.y;
  const int flat = blockIdx.y * NX + blockIdx.x;
  const int wid = (flat & 7) * (total >> 3) + (flat >> 3);
  const int nb = wid % NX;
  const int n0 = nb * 128, m0 = (wid / NX) * 128;

  const int h = lane >> 4, rlx = (lane & 15) ^ (h << 1);

  f32x4 acc[4][4];
#pragma unroll
  for (int i = 0; i < 4; ++i)
#pragma unroll
    for (int j = 0; j < 4; ++j) acc[i][j] = (f32x4)0.f;

  // A staging maps (2 chunks/thread)
  const int row0 = tid >> 2, cb = tid & 3, row1 = 64 + row0;
  const int unit0 = cb * 128 + (row0 ^ (cb << 1));
  const int unit1 = cb * 128 + (row1 ^ (cb << 1));
  // B gll wave bases
  const int gb0 = w * 64, gb1 = 256 + w * 64;

  float4 fr[4];   // staged f32 A regs
  u16x8 ur[2];    // staged bf16 A regs
  const int NT = NSEG * 32;

  auto stage = [&](int t, int buf) {
    const int seg = (NSEG == 2 && t >= 32) ? 1 : 0;
    const int kb = t - seg * 32, kl = kb << 5;
    {  // B: pre-tiled, contiguous gll
      const u16* Bt = (seg ? Bt1 : Bt0) + ((size_t)(nb * 32 + kb) * 512) * 8;
      llds16(Bt + (gb0 + lane) * 8, &Bs[buf][gb0 * 8]);
      llds16(Bt + (gb1 + lane) * 8, &Bs[buf][gb1 * 8]);
    }
    const bool abf = seg ? S1BF : S0BF;
    if (abf) {
      const u16* Ap = (const u16*)(seg ? A1v : A0v);
      ur[0] = *(const u16x8*)(Ap + (size_t)(m0 + row0) * lda + kl + cb * 8);
      ur[1] = *(const u16x8*)(Ap + (size_t)(m0 + row1) * lda + kl + cb * 8);
    } else {
      const float* Ap = (const float*)(seg ? A1v : A0v);
      const float* p0 = Ap + (size_t)(m0 + row0) * lda + kl + cb * 8;
      const float* p1 = Ap + (size_t)(m0 + row1) * lda + kl + cb * 8;
      fr[0] = *(const float4*)p0; fr[1] = *(const float4*)(p0 + 4);
      fr[2] = *(const float4*)p1; fr[3] = *(const float4*)(p1 + 4);
    }
  };
  auto stage_fin = [&](int t, int buf) {
    const int seg = (NSEG == 2 && t >= 32) ? 1 : 0;
    const bool abf = seg ? S1BF : S0BF;
    if (abf) {
      *(u16x8*)&As[buf][unit0 * 8] = ur[0];
      *(u16x8*)&As[buf][unit1 * 8] = ur[1];
    } else {
      *(bf16x8*)&As[buf][unit0 * 8] = cvt8(fr[0], fr[1]);
      *(bf16x8*)&As[buf][unit1 * 8] = cvt8(fr[2], fr[3]);
    }
  };
  auto compute = [&](int buf) {
    bf16x8 af[4], bfv[4];
#pragma unroll
    for (int i = 0; i < 4; ++i)
      af[i] = *(const bf16x8*)&As[buf][(h * 128 + wr * 64 + i * 16 + rlx) * 8];
#pragma unroll
    for (int j = 0; j < 4; ++j)
      bfv[j] = *(const bf16x8*)&Bs[buf][(h * 128 + wc * 64 + j * 16 + rlx) * 8];
#pragma unroll
    for (int i = 0; i < 4; ++i)
#pragma unroll
      for (int j = 0; j < 4; ++j)
        acc[i][j] =
            __builtin_amdgcn_mfma_f32_16x16x32_bf16(af[i], bfv[j], acc[i][j], 0, 0, 0);
  };

  stage(0, 0);
  stage_fin(0, 0);
  __syncthreads();
  for (int t = 0; t < NT; ++t) {
    const int cb_ = t & 1;
    if (t + 1 < NT) stage(t + 1, cb_ ^ 1);
    compute(cb_);
    if (t + 1 < NT) stage_fin(t + 1, cb_ ^ 1);
    __syncthreads();
  }

  // Epilogue. C/D: col = lane&15, row = (lane>>4)*4 + reg.
  const int rl = lane & 15, rq = lane >> 4;
#pragma unroll
  for (int j = 0; j < 4; ++j) {
    const int gc = n0 + wc * 64 + j * 16 + rl;
    float bia = 0.f;
    if (bias0) bia += bias0[gc];
    if (NSEG == 2 && bias1) bia += bias1[gc];
#pragma unroll
    for (int i = 0; i < 4; ++i) {
#pragma unroll
      for (int r = 0; r < 4; ++r) {
        const int grow = m0 + wr * 64 + i * 16 + rq * 4 + r;
        float v = acc[i][j][r] + bia;
        if (TANH) v = fast_tanh(v);
        if (OUT_BF16)
          ((u16*)Cout)[(size_t)grow * ldc + gc] = f2bf(v);
        else
          ((float*)Cout)[(size_t)grow * ldc + gc] = v;
      }
    }
  }
}

// ---------------------------------------------------------------------------
// NN GEMM (per batch): mix[l,d] = sum_w alpha[l,w]*ctx[w,d]; K=512.
// A = alpha f32 reg-staged (swizzled); B = ctx transposed into swizzled LDS.
// ---------------------------------------------------------------------------
template <bool CTXBF>
__global__ __launch_bounds__(256) void gemm_nn3(
    const float* __restrict__ alpha, const void* __restrict__ ctxv,
    u16* __restrict__ mix) {
  __shared__ u16 As[2][4096];
  __shared__ u16 Bs[2][4096];
  const int tid = threadIdx.x, lane = tid & 63, w = tid >> 6;
  const int wr = w >> 1, wc = w & 1;
  const int b = blockIdx.z;
  const int n0 = blockIdx.x * 128, m0 = blockIdx.y * 128;
  const int h = lane >> 4, rlx = (lane & 15) ^ (h << 1);
  const float* A = alpha + (size_t)b * 262144;  // [512,512]
  u16* C = mix + (size_t)b * 524288;            // [512,1024]

  f32x4 acc[4][4];
#pragma unroll
  for (int i = 0; i < 4; ++i)
#pragma unroll
    for (int j = 0; j < 4; ++j) acc[i][j] = (f32x4)0.f;

  const int row0 = tid >> 2, cb = tid & 3, row1 = 64 + row0;
  const int unit0 = cb * 128 + (row0 ^ (cb << 1));
  const int unit1 = cb * 128 + (row1 ^ (cb << 1));
  const int kl = tid & 31, ng = tid >> 5;  // B: k row, 16-col group
  const int hb = kl >> 3, kp = kl & 7;

  float4 fr[4];
  u16x8 ub[2];
  float4 fb[4];

  auto stage = [&](int t) {
    const int k0 = t << 5;
    const float* p0 = A + (size_t)(m0 + row0) * 512 + k0 + cb * 8;
    const float* p1 = A + (size_t)(m0 + row1) * 512 + k0 + cb * 8;
    fr[0] = *(const float4*)p0; fr[1] = *(const float4*)(p0 + 4);
    fr[2] = *(const float4*)p1; fr[3] = *(const float4*)(p1 + 4);
    if (CTXBF) {
      const u16* Cb = (const u16*)ctxv + (size_t)b * 524288 +
                      (size_t)(k0 + kl) * 1024 + n0 + ng * 16;
      ub[0] = *(const u16x8*)Cb; ub[1] = *(const u16x8*)(Cb + 8);
    } else {
      const float* Cf = (const float*)ctxv + (size_t)b * 524288 +
                        (size_t)(k0 + kl) * 1024 + n0 + ng * 16;
      fb[0] = *(const float4*)Cf;      fb[1] = *(const float4*)(Cf + 4);
      fb[2] = *(const float4*)(Cf + 8); fb[3] = *(const float4*)(Cf + 12);
    }
  };
  auto stage_fin = [&](int buf) {
    *(bf16x8*)&As[buf][unit0 * 8] = cvt8(fr[0], fr[1]);
    *(bf16x8*)&As[buf][unit1 * 8] = cvt8(fr[2], fr[3]);
    u16 vals[16];
    if (CTXBF) {
#pragma unroll
      for (int j = 0; j < 8; ++j) { vals[j] = ub[0][j]; vals[8 + j] = ub[1][j]; }
    } else {
      bf16x8 x = cvt8(fb[0], fb[1]), y = cvt8(fb[2], fb[3]);
#pragma unroll
      for (int j = 0; j < 8; ++j) {
        __bf16 hx = x[j], hy = y[j];
        vals[j] = *(const u16*)&hx; vals[8 + j] = *(const u16*)&hy;
      }
    }
#pragma unroll
    for (int j = 0; j < 16; ++j) {
      int n = ng * 16 + j;
      Bs[buf][(hb * 128 + (n ^ (hb << 1))) * 8 + kp] = vals[j];
    }
  };
  auto compute = [&](int buf) {
    bf16x8 af[4], bfv[4];
#pragma unroll
    for (int i = 0; i < 4; ++i)
      af[i] = *(const bf16x8*)&As[buf][(h * 128 + wr * 64 + i * 16 + rlx) * 8];
#pragma unroll
    for (int j = 0; j < 4; ++j)
      bfv[j] = *(const bf16x8*)&Bs[buf][(h * 128 + wc * 64 + j * 16 + rlx) * 8];
#pragma unroll
    for (int i = 0; i < 4; ++i)
#pragma unroll
      for (int j = 0; j < 4; ++j)
        acc[i][j] =
            __builtin_amdgcn_mfma_f32_16x16x32_bf16(af[i], bfv[j], acc[i][j], 0, 0, 0);
  };

  stage(0);
  stage_fin(0);
  __syncthreads();
  for (int t = 0; t < 16; ++t) {
    const int cb_ = t & 1;
    if (t + 1 < 16) stage(t + 1);
    compute(cb_);
    if (t + 1 < 16) stage_fin(cb_ ^ 1);
    __syncthreads();
  }

  const int rl = lane & 15, rq = lane >> 4;
#pragma unroll
  for (int j = 0; j < 4; ++j) {
    const int gc = n0 + wc * 64 + j * 16 + rl;
#pragma unroll
    for (int i = 0; i < 4; ++i) {
#pragma unroll
      for (int r = 0; r < 4; ++r) {
        const int grow = m0 + wr * 64 + i * 16 + rq * 4 + r;
        C[(size_t)grow * 1024 + gc] = f2bf(acc[i][j][r]);
      }
    }
  }
}

// ---------------------------------------------------------------------------
// Row softmax, in-place f32: one wave per row of 512
// ---------------------------------------------------------------------------
__global__ __launch_bounds__(256) void softmax_rows_f32(float* __restrict__ S) {
  const int row = blockIdx.x * 4 + (threadIdx.x >> 6);
  const int lane = threadIdx.x & 63;
  float* s = S + (size_t)row * 512 + lane * 8;
  float4 v0 = *(const float4*)s;
  float4 v1 = *(const float4*)(s + 4);
  float vs[8] = {v0.x, v0.y, v0.z, v0.w, v1.x, v1.y, v1.z, v1.w};
  float vm = vs[0];
#pragma unroll
  for (int j = 1; j < 8; ++j) vm = fmaxf(vm, vs[j]);
#pragma unroll
  for (int off = 32; off > 0; off >>= 1) vm = fmaxf(vm, __shfl_xor(vm, off, 64));
  float e[8];
  float sum = 0.f;
#pragma unroll
  for (int j = 0; j < 8; ++j) { e[j] = __expf(vs[j] - vm); sum += e[j]; }
#pragma unroll
  for (int off = 32; off > 0; off >>= 1) sum += __shfl_xor(sum, off, 64);
  float inv = 1.f / sum;
  float4 o0 = {e[0] * inv, e[1] * inv, e[2] * inv, e[3] * inv};
  float4 o1 = {e[4] * inv, e[5] * inv, e[6] * inv, e[7] * inv};
  *(float4*)s = o0;
  *(float4*)(s + 4) = o1;
}

// ---------------------------------------------------------------------------
extern "C" void kernel_launch(void* const* d_in, const int* in_sizes, int n_in,
                              void* d_out, int out_size, void* d_ws, size_t ws_size,
                              hipStream_t stream) {
  const float* query = (const float*)d_in[0];  // [32,512,1024] f32
  const float* ctx   = (const float*)d_in[1];  // [32,512,1024]
  const float* W_in  = (const float*)d_in[2];  // [1024,1024]
  const float* b_in  = (const float*)d_in[3];  // [1024]
  const float* W_in2 = (const float*)d_in[4];  // [1024,1024]
  const float* b_in2 = (const float*)d_in[5];  // [1024]
  const float* W_out = (const float*)d_in[6];  // [512,1024]
  const float* W_fc  = (const float*)d_in[7];  // [1024,2048]
  const float* b_fc  = (const float*)d_in[8];  // [1024]

  float* out   = (float*)d_out;               // [32*512*1024] f32
  float* alpha = (float*)d_out + 16777216;    // [32*512*512] f32 (scores too)

  // ws: [tiled weights 9.4MB][t/mix 33.55MB][cbf 33.55MB planB]
  u16* wibf_t  = (u16*)d_ws;                 // 1048576
  u16* wi2bf_t = wibf_t + 1048576;           // 1048576
  u16* wobf_t  = wibf_t + 2097152;           // 524288
  u16* wf0_t   = wibf_t + 2621440;           // 1048576
  u16* wf1_t   = wibf_t + 3670016;           // 1048576
  u16* t_ws    = (u16*)((char*)d_ws + 9437184);   // 16777216 u16 (t, then mix)
  u16* cbf     = (u16*)((char*)d_ws + 42991616);  // 16777216 u16
  const bool planB = ws_size >= 76546048ull;

  dim3 blk(256, 1, 1);

  // K0: tile+convert weights (+ ctx natural-bf16 if plan B)
  tile_b<<<dim3(512), blk, 0, stream>>>(W_in, 1024, 0, wibf_t, 131072);
  tile_b<<<dim3(512), blk, 0, stream>>>(W_in2, 1024, 0, wi2bf_t, 131072);
  tile_b<<<dim3(256), blk, 0, stream>>>(W_out, 1024, 0, wobf_t, 65536);
  tile_b<<<dim3(512), blk, 0, stream>>>(W_fc, 2048, 0, wf0_t, 131072);
  tile_b<<<dim3(512), blk, 0, stream>>>(W_fc, 2048, 1024, wf1_t, 131072);
  if (planB) cvtk<<<dim3(8192), blk, 0, stream>>>(ctx, cbf, 2097152);

  // K1: t = tanh(query@W_in^T + ctx@W_in2^T + b_in + b_in2) -> bf16
  if (planB)
    gemm_nt3<2, false, true, true, true><<<dim3(8, 128), blk, 0, stream>>>(
        query, cbf, 1024, wibf_t, wi2bf_t, b_in, b_in2, t_ws, 1024);
  else
    gemm_nt3<2, false, false, true, true><<<dim3(8, 128), blk, 0, stream>>>(
        query, ctx, 1024, wibf_t, wi2bf_t, b_in, b_in2, t_ws, 1024);

  // K2: scores = t @ W_out^T -> f32 into alpha slot
  gemm_nt3<1, true, true, false, false><<<dim3(4, 128), blk, 0, stream>>>(
      t_ws, nullptr, 1024, wobf_t, nullptr, nullptr, nullptr, alpha, 512);

  // K3: softmax in-place
  softmax_rows_f32<<<dim3(4096), blk, 0, stream>>>(alpha);

  // K4: mix = alpha @ ctx -> bf16 (t region; t dead after K2)
  if (planB)
    gemm_nn3<true><<<dim3(8, 4, 32), blk, 0, stream>>>(alpha, cbf, t_ws);
  else
    gemm_nn3<false><<<dim3(8, 4, 32), blk, 0, stream>>>(alpha, ctx, t_ws);

  // K5: out = mix@W_fc[:, :1024]^T + ctx@W_fc[:, 1024:]^T + b_fc -> f32
  if (planB)
    gemm_nt3<2, true, true, false, false><<<dim3(8, 128), blk, 0, stream>>>(
        t_ws, cbf, 1024, wf0_t, wf1_t, b_fc, nullptr, out, 1024);
  else
    gemm_nt3<2, true, false, false, false><<<dim3(8, 128), blk, 0, stream>>>(
        t_ws, ctx, 1024, wf0_t, wf1_t, b_fc, nullptr, out, 1024);
}